// Round 1
// baseline (2811.714 us; speedup 1.0000x reference)
//
#include <hip/hip_runtime.h>

// ModularPathwayConv: per-edge 2-layer MLP on [x_i*ea ; x_j] then scatter-add to col.
// Round 1: fp32 edge-per-lane, weights in LDS (wave-uniform broadcast reads),
// h[64] in VGPRs, atomicAdd scatter. Expected VALU-bound ~150-350us.

constexpr int TPB = 256;

__global__ __launch_bounds__(TPB) void edge_mlp_atomic(
    const float* __restrict__ x,
    const int* __restrict__ ei,
    const float* __restrict__ eattr,
    const float* __restrict__ W1,
    const float* __restrict__ b1,
    const float* __restrict__ W2,
    const float* __restrict__ b2,
    float* __restrict__ out,
    int E)
{
  __shared__ float sW1[128 * 64];
  __shared__ float sW2[64 * 64];
  __shared__ float sB1[64];
  __shared__ float sB2[64];

  for (int i = threadIdx.x; i < 128 * 64 / 4; i += TPB)
    reinterpret_cast<float4*>(sW1)[i] = reinterpret_cast<const float4*>(W1)[i];
  for (int i = threadIdx.x; i < 64 * 64 / 4; i += TPB)
    reinterpret_cast<float4*>(sW2)[i] = reinterpret_cast<const float4*>(W2)[i];
  if (threadIdx.x < 64) {
    sB1[threadIdx.x] = b1[threadIdx.x];
    sB2[threadIdx.x] = b2[threadIdx.x];
  }
  __syncthreads();

  const int e = blockIdx.x * TPB + (int)threadIdx.x;
  if (e >= E) return;

  const int row = ei[e];        // source: gathered, scaled by edge_attr
  const int col = ei[E + e];    // target: gathered + scatter destination
  const float scale = eattr[e];

  float h[64];
#pragma unroll
  for (int o = 0; o < 64; o += 4) {
    float4 b = *reinterpret_cast<const float4*>(sB1 + o);
    h[o] = b.x; h[o + 1] = b.y; h[o + 2] = b.z; h[o + 3] = b.w;
  }

  // Layer 1: h += [x_i ; x_j] @ W1   (W1 is [128,64] row-major)
#pragma unroll
  for (int half = 0; half < 2; ++half) {
    const float4* src =
        reinterpret_cast<const float4*>(x + (size_t)(half ? col : row) * 64);
    const float sc = half ? 1.0f : scale;
    const float* wb = sW1 + half * 64 * 64;
    for (int kc = 0; kc < 16; ++kc) {   // 16 chunks of 4 input channels
      float4 cv = src[kc];
      cv.x *= sc; cv.y *= sc; cv.z *= sc; cv.w *= sc;
      const float* wr = wb + kc * 4 * 64;
#pragma unroll
      for (int kk = 0; kk < 4; ++kk) {
        const float c = (&cv.x)[kk];
#pragma unroll
        for (int o = 0; o < 64; o += 4) {
          // wave-uniform address -> ds_read_b128 broadcast, conflict-free
          float4 w = *reinterpret_cast<const float4*>(wr + kk * 64 + o);
          h[o]     = fmaf(c, w.x, h[o]);
          h[o + 1] = fmaf(c, w.y, h[o + 1]);
          h[o + 2] = fmaf(c, w.z, h[o + 2]);
          h[o + 3] = fmaf(c, w.w, h[o + 3]);
        }
      }
    }
  }

#pragma unroll
  for (int o = 0; o < 64; ++o) h[o] = fmaxf(h[o], 0.0f);

  // Layer 2: msg = relu(h) @ W2 + b2, in chunks of 16 outputs to cap VGPRs
  float* outrow = out + (size_t)col * 64;
#pragma unroll
  for (int oc = 0; oc < 4; ++oc) {
    float m[16];
#pragma unroll
    for (int j = 0; j < 16; j += 4) {
      float4 b = *reinterpret_cast<const float4*>(sB2 + oc * 16 + j);
      m[j] = b.x; m[j + 1] = b.y; m[j + 2] = b.z; m[j + 3] = b.w;
    }
#pragma unroll
    for (int k = 0; k < 64; ++k) {
      const float hk = h[k];
      const float* wr = sW2 + k * 64 + oc * 16;
#pragma unroll
      for (int j = 0; j < 16; j += 4) {
        float4 w = *reinterpret_cast<const float4*>(wr + j);
        m[j]     = fmaf(hk, w.x, m[j]);
        m[j + 1] = fmaf(hk, w.y, m[j + 1]);
        m[j + 2] = fmaf(hk, w.z, m[j + 2]);
        m[j + 3] = fmaf(hk, w.w, m[j + 3]);
      }
    }
#pragma unroll
    for (int j = 0; j < 16; ++j)
      atomicAdd(outrow + oc * 16 + j, m[j]);
  }
}

extern "C" void kernel_launch(void* const* d_in, const int* in_sizes, int n_in,
                              void* d_out, int out_size, void* d_ws, size_t ws_size,
                              hipStream_t stream) {
  const float* x  = (const float*)d_in[0];
  const int*   ei = (const int*)d_in[1];   // [2, E] int32 (JAX x64 disabled)
  const float* ea = (const float*)d_in[2];
  const float* W1 = (const float*)d_in[3];
  const float* b1 = (const float*)d_in[4];
  const float* W2 = (const float*)d_in[5];
  const float* b2 = (const float*)d_in[6];
  float* out = (float*)d_out;
  const int E = in_sizes[2];   // edge_attr element count

  // d_out is poisoned 0xAA before every launch -> zero it (atomic accumulate target)
  hipMemsetAsync(d_out, 0, (size_t)out_size * sizeof(float), stream);

  const int blocks = (E + TPB - 1) / TPB;
  edge_mlp_atomic<<<blocks, TPB, 0, stream>>>(x, ei, ea, W1, b1, W2, b2, out, E);
}

// Round 2
// 723.661 us; speedup vs baseline: 3.8854x; 3.8854x over previous
//
#include <hip/hip_runtime.h>

// ModularPathwayConv round 2:
// R1 post-mortem: 2745us, VALUBusy 6.4%, WRITE_SIZE 1.6GB = 51.2M fp32 atomics
// x 32B HBM write-through. Fix: device counting-sort edges by col, then
// segmented in-wave reduction -> ~7M clustered atomics instead of 51.2M random.

constexpr int TPB = 256;
constexpr int SCAN_B = 1024;

// ---------------- sort-by-col pipeline ----------------

__global__ void hist_kernel(const int* __restrict__ ei, int* __restrict__ cnt, int E) {
  int e = blockIdx.x * blockDim.x + threadIdx.x;
  if (e < E) atomicAdd(&cnt[ei[E + e]], 1);
}

__global__ __launch_bounds__(SCAN_B) void scan_local(int* __restrict__ off,
                                                     int* __restrict__ bsum, int N) {
  __shared__ int s[SCAN_B];
  int i = blockIdx.x * SCAN_B + (int)threadIdx.x;
  int v = (i < N) ? off[i] : 0;
  s[threadIdx.x] = v;
  __syncthreads();
  for (int d = 1; d < SCAN_B; d <<= 1) {
    int t = (threadIdx.x >= d) ? s[threadIdx.x - d] : 0;
    __syncthreads();
    s[threadIdx.x] += t;
    __syncthreads();
  }
  if (i < N) off[i] = s[threadIdx.x] - v;            // block-local exclusive
  if (threadIdx.x == SCAN_B - 1) bsum[blockIdx.x] = s[threadIdx.x];  // block total
}

__global__ __launch_bounds__(SCAN_B) void scan_bsum(int* __restrict__ bsum, int nb) {
  __shared__ int s[SCAN_B];
  int v = ((int)threadIdx.x < nb) ? bsum[threadIdx.x] : 0;
  s[threadIdx.x] = v;
  __syncthreads();
  for (int d = 1; d < SCAN_B; d <<= 1) {
    int t = (threadIdx.x >= d) ? s[threadIdx.x - d] : 0;
    __syncthreads();
    s[threadIdx.x] += t;
    __syncthreads();
  }
  if ((int)threadIdx.x < nb) bsum[threadIdx.x] = s[threadIdx.x] - v;  // exclusive
}

__global__ void scatter_sort(const int* __restrict__ ei, const float* __restrict__ ea,
                             int* __restrict__ off, const int* __restrict__ bsum,
                             int* __restrict__ srow, int* __restrict__ scol,
                             float* __restrict__ sea, int E) {
  int e = blockIdx.x * blockDim.x + threadIdx.x;
  if (e >= E) return;
  int col = ei[E + e];
  int pos = atomicAdd(&off[col], 1) + bsum[col >> 10];
  srow[pos] = ei[e];
  scol[pos] = col;
  sea[pos] = ea[e];
}

// ---------------- fused MLP + segmented scatter ----------------

__global__ __launch_bounds__(TPB) void edge_mlp_sorted(
    const float* __restrict__ x,
    const int* __restrict__ srow,
    const int* __restrict__ scol,
    const float* __restrict__ sea,
    const float* __restrict__ W1,
    const float* __restrict__ b1,
    const float* __restrict__ W2,
    const float* __restrict__ b2,
    float* __restrict__ out,
    int E)
{
  __shared__ float sW1[128 * 64];
  __shared__ float sW2[64 * 64];
  __shared__ float sB1[64];
  __shared__ float sB2[64];

  for (int i = threadIdx.x; i < 128 * 64 / 4; i += TPB)
    reinterpret_cast<float4*>(sW1)[i] = reinterpret_cast<const float4*>(W1)[i];
  for (int i = threadIdx.x; i < 64 * 64 / 4; i += TPB)
    reinterpret_cast<float4*>(sW2)[i] = reinterpret_cast<const float4*>(W2)[i];
  if (threadIdx.x < 64) {
    sB1[threadIdx.x] = b1[threadIdx.x];
    sB2[threadIdx.x] = b2[threadIdx.x];
  }
  __syncthreads();

  const int p = blockIdx.x * TPB + (int)threadIdx.x;
  const bool valid = p < E;
  const int lane = threadIdx.x & 63;

  // sentinel col=-1 for tail lanes: never matches a valid col, never written
  const int col = valid ? scol[p] : -1;
  const int row = valid ? srow[p] : 0;
  const float scale = valid ? sea[p] : 0.0f;

  float h[64];
#pragma unroll
  for (int o = 0; o < 64; o += 4) {
    float4 b = *reinterpret_cast<const float4*>(sB1 + o);
    h[o] = b.x; h[o + 1] = b.y; h[o + 2] = b.z; h[o + 3] = b.w;
  }

  // Layer 1: h += [x_i*ea ; x_j] @ W1   (W1 is [128,64] row-major)
#pragma unroll
  for (int half = 0; half < 2; ++half) {
    const float4* src =
        reinterpret_cast<const float4*>(x + (size_t)(half ? col : row) * 64);
    // note: for invalid lanes col=-1 -> read x[0] instead (harmless)
    const float4* safesrc = valid ? src : reinterpret_cast<const float4*>(x);
    const float sc = half ? 1.0f : scale;
    const float* wb = sW1 + half * 64 * 64;
    for (int kc = 0; kc < 16; ++kc) {
      float4 cv = safesrc[kc];
      cv.x *= sc; cv.y *= sc; cv.z *= sc; cv.w *= sc;
      const float* wr = wb + kc * 4 * 64;
#pragma unroll
      for (int kk = 0; kk < 4; ++kk) {
        const float c = (&cv.x)[kk];
#pragma unroll
        for (int o = 0; o < 64; o += 4) {
          // wave-uniform address -> LDS broadcast, conflict-free
          float4 w = *reinterpret_cast<const float4*>(wr + kk * 64 + o);
          h[o]     = fmaf(c, w.x, h[o]);
          h[o + 1] = fmaf(c, w.y, h[o + 1]);
          h[o + 2] = fmaf(c, w.z, h[o + 2]);
          h[o + 3] = fmaf(c, w.w, h[o + 3]);
        }
      }
    }
  }

#pragma unroll
  for (int o = 0; o < 64; ++o) h[o] = fmaxf(h[o], 0.0f);

  // Segmented-reduction setup: cols are sorted, runs are contiguous.
  const int colup = __shfl_up(col, 1);
  const bool writer = valid && (lane == 0 || colup != col);
  bool take[6];
#pragma unroll
  for (int s = 0; s < 6; ++s) {
    const int d = 1 << s;
    const int cd = __shfl_down(col, d);
    take[s] = (lane + d < 64) && (cd == col);
  }

  // Layer 2 in chunks of 16 outputs; segmented suffix-sum over the wave;
  // only run-leader lanes issue atomics.
#pragma unroll
  for (int oc = 0; oc < 4; ++oc) {
    float m[16];
#pragma unroll
    for (int j = 0; j < 16; j += 4) {
      float4 b = *reinterpret_cast<const float4*>(sB2 + oc * 16 + j);
      m[j] = b.x; m[j + 1] = b.y; m[j + 2] = b.z; m[j + 3] = b.w;
    }
#pragma unroll
    for (int k = 0; k < 64; ++k) {
      const float hk = h[k];
      const float* wr = sW2 + k * 64 + oc * 16;
#pragma unroll
      for (int j = 0; j < 16; j += 4) {
        float4 w = *reinterpret_cast<const float4*>(wr + j);
        m[j]     = fmaf(hk, w.x, m[j]);
        m[j + 1] = fmaf(hk, w.y, m[j + 1]);
        m[j + 2] = fmaf(hk, w.z, m[j + 2]);
        m[j + 3] = fmaf(hk, w.w, m[j + 3]);
      }
    }
    // segmented suffix reduction: m[lane] += m[lane+d] while same col
#pragma unroll
    for (int s = 0; s < 6; ++s) {
      const int d = 1 << s;
#pragma unroll
      for (int j = 0; j < 16; ++j) {
        const float t = __shfl_down(m[j], d);
        m[j] += take[s] ? t : 0.0f;
      }
    }
    if (writer) {
      float* orow = out + (size_t)col * 64 + oc * 16;
#pragma unroll
      for (int j = 0; j < 16; ++j) atomicAdd(orow + j, m[j]);
    }
  }
}

// ---------------- fallback (round-1 path, if ws too small) ----------------

__global__ __launch_bounds__(TPB) void edge_mlp_atomic(
    const float* __restrict__ x, const int* __restrict__ ei,
    const float* __restrict__ eattr, const float* __restrict__ W1,
    const float* __restrict__ b1, const float* __restrict__ W2,
    const float* __restrict__ b2, float* __restrict__ out, int E)
{
  __shared__ float sW1[128 * 64];
  __shared__ float sW2[64 * 64];
  __shared__ float sB1[64];
  __shared__ float sB2[64];
  for (int i = threadIdx.x; i < 128 * 64 / 4; i += TPB)
    reinterpret_cast<float4*>(sW1)[i] = reinterpret_cast<const float4*>(W1)[i];
  for (int i = threadIdx.x; i < 64 * 64 / 4; i += TPB)
    reinterpret_cast<float4*>(sW2)[i] = reinterpret_cast<const float4*>(W2)[i];
  if (threadIdx.x < 64) { sB1[threadIdx.x] = b1[threadIdx.x]; sB2[threadIdx.x] = b2[threadIdx.x]; }
  __syncthreads();
  const int e = blockIdx.x * TPB + (int)threadIdx.x;
  if (e >= E) return;
  const int row = ei[e];
  const int col = ei[E + e];
  const float scale = eattr[e];
  float h[64];
#pragma unroll
  for (int o = 0; o < 64; ++o) h[o] = sB1[o];
#pragma unroll
  for (int half = 0; half < 2; ++half) {
    const float4* src = reinterpret_cast<const float4*>(x + (size_t)(half ? col : row) * 64);
    const float sc = half ? 1.0f : scale;
    const float* wb = sW1 + half * 64 * 64;
    for (int kc = 0; kc < 16; ++kc) {
      float4 cv = src[kc];
      cv.x *= sc; cv.y *= sc; cv.z *= sc; cv.w *= sc;
      const float* wr = wb + kc * 4 * 64;
#pragma unroll
      for (int kk = 0; kk < 4; ++kk) {
        const float c = (&cv.x)[kk];
#pragma unroll
        for (int o = 0; o < 64; ++o) h[o] = fmaf(c, wr[kk * 64 + o], h[o]);
      }
    }
  }
#pragma unroll
  for (int o = 0; o < 64; ++o) h[o] = fmaxf(h[o], 0.0f);
  float* outrow = out + (size_t)col * 64;
#pragma unroll
  for (int oc = 0; oc < 4; ++oc) {
    float m[16];
#pragma unroll
    for (int j = 0; j < 16; ++j) m[j] = sB2[oc * 16 + j];
#pragma unroll
    for (int k = 0; k < 64; ++k) {
      const float hk = h[k];
      const float* wr = sW2 + k * 64 + oc * 16;
#pragma unroll
      for (int j = 0; j < 16; ++j) m[j] = fmaf(hk, wr[j], m[j]);
    }
#pragma unroll
    for (int j = 0; j < 16; ++j) atomicAdd(outrow + oc * 16 + j, m[j]);
  }
}

// ---------------- launch ----------------

extern "C" void kernel_launch(void* const* d_in, const int* in_sizes, int n_in,
                              void* d_out, int out_size, void* d_ws, size_t ws_size,
                              hipStream_t stream) {
  const float* x  = (const float*)d_in[0];
  const int*   ei = (const int*)d_in[1];   // [2, E] int32
  const float* ea = (const float*)d_in[2];
  const float* W1 = (const float*)d_in[3];
  const float* b1 = (const float*)d_in[4];
  const float* W2 = (const float*)d_in[5];
  const float* b2 = (const float*)d_in[6];
  float* out = (float*)d_out;
  const int E = in_sizes[2];
  const int N = in_sizes[0] / 64;
  const int nb = (N + SCAN_B - 1) / SCAN_B;   // scan blocks (98 for N=100000)

  hipMemsetAsync(d_out, 0, (size_t)out_size * sizeof(float), stream);

  // ws layout: off[N] | bsum[SCAN_B] | srow[E] | scol[E] | sea[E]
  const size_t need = ((size_t)N + SCAN_B + 3 * (size_t)E) * 4;
  if (ws_size < need || nb > SCAN_B) {
    // fallback: round-1 atomic kernel
    const int blocks = (E + TPB - 1) / TPB;
    edge_mlp_atomic<<<blocks, TPB, 0, stream>>>(x, ei, ea, W1, b1, W2, b2, out, E);
    return;
  }

  int* off   = (int*)d_ws;
  int* bsum  = off + N;
  int* srow  = bsum + SCAN_B;
  int* scol  = srow + E;
  float* sea = (float*)(scol + E);

  hipMemsetAsync(off, 0, (size_t)N * sizeof(int), stream);

  const int eblocks = (E + TPB - 1) / TPB;
  hist_kernel<<<eblocks, TPB, 0, stream>>>(ei, off, E);
  scan_local<<<nb, SCAN_B, 0, stream>>>(off, bsum, N);
  scan_bsum<<<1, SCAN_B, 0, stream>>>(bsum, nb);
  scatter_sort<<<eblocks, TPB, 0, stream>>>(ei, ea, off, bsum, srow, scol, sea, E);
  edge_mlp_sorted<<<eblocks, TPB, 0, stream>>>(x, srow, scol, sea,
                                               W1, b1, W2, b2, out, E);
}

// Round 3
// 272.781 us; speedup vs baseline: 10.3076x; 2.6529x over previous
//
#include <hip/hip_runtime.h>

// ModularPathwayConv round 3: algebraic restructure.
//  h_e = relu(ea*A[row] + Bp[col]),  A = x@W1_top, Bp = x@W1_bot + b1
//  out[n] = (sum_e h_e) @ W2 + deg[n]*b2   (second GEMM deferred past scatter)
// CSR (hist+scan+scatter of (row,ea)) -> node-centric accumulate, ZERO atomics
// in the hot kernel. R2 post-mortem: 617us was atomic write-through (222MB) +
// latency-bound gathers; this cuts per-edge FLOPs 3x and writes 8.7x.

constexpr int TPB = 256;
constexpr int SCAN_B = 1024;

// ---------------- CSR build ----------------

__global__ void hist_kernel(const int* __restrict__ ei, int* __restrict__ cnt, int E) {
  int e = blockIdx.x * blockDim.x + threadIdx.x;
  if (e < E) atomicAdd(&cnt[ei[E + e]], 1);
}

// off[i] = block-local exclusive scan of cnt; bsum[b] = block total (cnt preserved)
__global__ __launch_bounds__(SCAN_B) void scan_local(const int* __restrict__ cnt,
                                                     int* __restrict__ off,
                                                     int* __restrict__ bsum, int N) {
  __shared__ int s[SCAN_B];
  int i = blockIdx.x * SCAN_B + (int)threadIdx.x;
  int v = (i < N) ? cnt[i] : 0;
  s[threadIdx.x] = v;
  __syncthreads();
  for (int d = 1; d < SCAN_B; d <<= 1) {
    int t = (threadIdx.x >= d) ? s[threadIdx.x - d] : 0;
    __syncthreads();
    s[threadIdx.x] += t;
    __syncthreads();
  }
  if (i < N) off[i] = s[threadIdx.x] - v;
  if (threadIdx.x == SCAN_B - 1) bsum[blockIdx.x] = s[threadIdx.x];
}

__global__ __launch_bounds__(SCAN_B) void scan_bsum(int* __restrict__ bsum, int nb) {
  __shared__ int s[SCAN_B];
  int v = ((int)threadIdx.x < nb) ? bsum[threadIdx.x] : 0;
  s[threadIdx.x] = v;
  __syncthreads();
  for (int d = 1; d < SCAN_B; d <<= 1) {
    int t = (threadIdx.x >= d) ? s[threadIdx.x - d] : 0;
    __syncthreads();
    s[threadIdx.x] += t;
    __syncthreads();
  }
  if ((int)threadIdx.x < nb) bsum[threadIdx.x] = s[threadIdx.x] - v;
}

// sre[pos] = (row, ea) packed, pos within the col's CSR segment
__global__ void scatter_edges(const int* __restrict__ ei, const float* __restrict__ ea,
                              const int* __restrict__ off, const int* __restrict__ bsum,
                              int* __restrict__ posc, int2* __restrict__ sre, int E) {
  int e = blockIdx.x * blockDim.x + threadIdx.x;
  if (e >= E) return;
  int col = ei[E + e];
  int pos = off[col] + bsum[col >> 10] + atomicAdd(&posc[col], 1);
  sre[pos] = make_int2(ei[e], __float_as_int(ea[e]));
}

// ---------------- per-node precompute: A = x@W1_top, Bp = x@W1_bot + b1 ----------------
// 4 lanes per node, 16 output channels per lane.

__global__ __launch_bounds__(TPB) void precompute_ab(
    const float* __restrict__ x, const float* __restrict__ W1,
    const float* __restrict__ b1, float* __restrict__ A, float* __restrict__ Bp, int N)
{
  __shared__ float sW1[128 * 64];   // 32 KB
  __shared__ float sB1[64];
  for (int i = threadIdx.x; i < 128 * 64 / 4; i += TPB)
    reinterpret_cast<float4*>(sW1)[i] = reinterpret_cast<const float4*>(W1)[i];
  if (threadIdx.x < 64) sB1[threadIdx.x] = b1[threadIdx.x];
  __syncthreads();

  const int g = blockIdx.x * TPB + (int)threadIdx.x;
  const int n = g >> 2;
  const int q = g & 3;               // channel quarter: [16q, 16q+16)
  if (n >= N) return;

  float4 aa[4], bb[4];
#pragma unroll
  for (int c = 0; c < 4; ++c) {
    aa[c] = make_float4(0.f, 0.f, 0.f, 0.f);
    bb[c] = *reinterpret_cast<const float4*>(sB1 + q * 16 + c * 4);
  }

  const float4* xrow = reinterpret_cast<const float4*>(x + (size_t)n * 64);
  for (int kc = 0; kc < 16; ++kc) {
    float4 xv = xrow[kc];            // 4 lanes of node read same addr -> one fetch
#pragma unroll
    for (int kk = 0; kk < 4; ++kk) {
      const float c0 = (&xv.x)[kk];
      const int k = kc * 4 + kk;
      const float* wa = sW1 + k * 64 + q * 16;
      const float* wb = sW1 + (64 + k) * 64 + q * 16;
#pragma unroll
      for (int c = 0; c < 4; ++c) {
        float4 wav = *reinterpret_cast<const float4*>(wa + c * 4);
        float4 wbv = *reinterpret_cast<const float4*>(wb + c * 4);
        aa[c].x = fmaf(c0, wav.x, aa[c].x); aa[c].y = fmaf(c0, wav.y, aa[c].y);
        aa[c].z = fmaf(c0, wav.z, aa[c].z); aa[c].w = fmaf(c0, wav.w, aa[c].w);
        bb[c].x = fmaf(c0, wbv.x, bb[c].x); bb[c].y = fmaf(c0, wbv.y, bb[c].y);
        bb[c].z = fmaf(c0, wbv.z, bb[c].z); bb[c].w = fmaf(c0, wbv.w, bb[c].w);
      }
    }
  }
  float4* arow = reinterpret_cast<float4*>(A + (size_t)n * 64) + q * 4;
  float4* brow = reinterpret_cast<float4*>(Bp + (size_t)n * 64) + q * 4;
#pragma unroll
  for (int c = 0; c < 4; ++c) { arow[c] = aa[c]; brow[c] = bb[c]; }
}

// ---------------- node-centric accumulate: H[n] = sum relu(ea*A[row]+Bp[n]) ----------------
// 4 lanes per node; zero atomics; one coalesced write per row.

__global__ __launch_bounds__(TPB) void node_accum(
    const float* __restrict__ A, const float* __restrict__ Bp,
    const int2* __restrict__ sre, const int* __restrict__ off,
    const int* __restrict__ bsum, const int* __restrict__ cnt,
    float* __restrict__ H, int N)
{
  const int g = blockIdx.x * TPB + (int)threadIdx.x;
  const int n = g >> 2;
  const int q = g & 3;
  if (n >= N) return;

  const int start = off[n] + bsum[n >> 10];
  const int deg = cnt[n];

  float4 bp[4];
  {
    const float4* brow = reinterpret_cast<const float4*>(Bp + (size_t)n * 64) + q * 4;
#pragma unroll
    for (int c = 0; c < 4; ++c) bp[c] = brow[c];
  }
  float4 acc[4];
#pragma unroll
  for (int c = 0; c < 4; ++c) acc[c] = make_float4(0.f, 0.f, 0.f, 0.f);

  int2 ed = (deg > 0) ? sre[start] : make_int2(0, 0);
  for (int t = 0; t < deg; ++t) {
    const int2 cur = ed;
    if (t + 1 < deg) ed = sre[start + t + 1];          // prefetch next edge
    const float eav = __int_as_float(cur.y);
    const float4* arow =
        reinterpret_cast<const float4*>(A + (size_t)cur.x * 64) + q * 4;
    float4 a0 = arow[0], a1 = arow[1], a2 = arow[2], a3 = arow[3];
#define STEP(av, c)                                                           \
    {                                                                         \
      float hx = fmaf(eav, av.x, bp[c].x); float hy = fmaf(eav, av.y, bp[c].y);\
      float hz = fmaf(eav, av.z, bp[c].z); float hw = fmaf(eav, av.w, bp[c].w);\
      acc[c].x += fmaxf(hx, 0.f); acc[c].y += fmaxf(hy, 0.f);                 \
      acc[c].z += fmaxf(hz, 0.f); acc[c].w += fmaxf(hw, 0.f);                 \
    }
    STEP(a0, 0) STEP(a1, 1) STEP(a2, 2) STEP(a3, 3)
#undef STEP
  }

  float4* hrow = reinterpret_cast<float4*>(H + (size_t)n * 64) + q * 4;
#pragma unroll
  for (int c = 0; c < 4; ++c) hrow[c] = acc[c];
}

// ---------------- final GEMM: out[n] = H[n]@W2 + deg*b2 (in-place on H==out) ----------------

__global__ __launch_bounds__(TPB) void final_gemm(
    float* __restrict__ H, const float* __restrict__ W2,
    const float* __restrict__ b2, const int* __restrict__ cnt, int N)
{
  __shared__ float sW2[64 * 64];    // 16 KB
  __shared__ float sB2[64];
  for (int i = threadIdx.x; i < 64 * 64 / 4; i += TPB)
    reinterpret_cast<float4*>(sW2)[i] = reinterpret_cast<const float4*>(W2)[i];
  if (threadIdx.x < 64) sB2[threadIdx.x] = b2[threadIdx.x];
  __syncthreads();

  const int g = blockIdx.x * TPB + (int)threadIdx.x;
  const int n = g >> 2;
  const int q = g & 3;
  if (n >= N) return;

  const float degf = (float)cnt[n];
  float4 m[4];
#pragma unroll
  for (int c = 0; c < 4; ++c) {
    float4 b = *reinterpret_cast<const float4*>(sB2 + q * 16 + c * 4);
    m[c] = make_float4(degf * b.x, degf * b.y, degf * b.z, degf * b.w);
  }

  const float4* hrow = reinterpret_cast<const float4*>(H + (size_t)n * 64);
  for (int kc = 0; kc < 16; ++kc) {
    float4 hv = hrow[kc];           // 4 lanes same addr -> broadcast
#pragma unroll
    for (int kk = 0; kk < 4; ++kk) {
      const float hk = (&hv.x)[kk];
      const float* wr = sW2 + (kc * 4 + kk) * 64 + q * 16;
#pragma unroll
      for (int c = 0; c < 4; ++c) {
        float4 w = *reinterpret_cast<const float4*>(wr + c * 4);
        m[c].x = fmaf(hk, w.x, m[c].x); m[c].y = fmaf(hk, w.y, m[c].y);
        m[c].z = fmaf(hk, w.z, m[c].z); m[c].w = fmaf(hk, w.w, m[c].w);
      }
    }
  }
  // lockstep within the wave: all 4 lanes' reads of this row precede stores
  float4* orow = reinterpret_cast<float4*>(H + (size_t)n * 64) + q * 4;
#pragma unroll
  for (int c = 0; c < 4; ++c) orow[c] = m[c];
}

// ---------------- fallback (round-1 path, if ws too small) ----------------

__global__ __launch_bounds__(TPB) void edge_mlp_atomic(
    const float* __restrict__ x, const int* __restrict__ ei,
    const float* __restrict__ eattr, const float* __restrict__ W1,
    const float* __restrict__ b1, const float* __restrict__ W2,
    const float* __restrict__ b2, float* __restrict__ out, int E)
{
  __shared__ float sW1[128 * 64];
  __shared__ float sW2[64 * 64];
  __shared__ float sB1[64];
  __shared__ float sB2[64];
  for (int i = threadIdx.x; i < 128 * 64 / 4; i += TPB)
    reinterpret_cast<float4*>(sW1)[i] = reinterpret_cast<const float4*>(W1)[i];
  for (int i = threadIdx.x; i < 64 * 64 / 4; i += TPB)
    reinterpret_cast<float4*>(sW2)[i] = reinterpret_cast<const float4*>(W2)[i];
  if (threadIdx.x < 64) { sB1[threadIdx.x] = b1[threadIdx.x]; sB2[threadIdx.x] = b2[threadIdx.x]; }
  __syncthreads();
  const int e = blockIdx.x * TPB + (int)threadIdx.x;
  if (e >= E) return;
  const int row = ei[e];
  const int col = ei[E + e];
  const float scale = eattr[e];
  float h[64];
#pragma unroll
  for (int o = 0; o < 64; ++o) h[o] = sB1[o];
#pragma unroll
  for (int half = 0; half < 2; ++half) {
    const float4* src = reinterpret_cast<const float4*>(x + (size_t)(half ? col : row) * 64);
    const float sc = half ? 1.0f : scale;
    const float* wb = sW1 + half * 64 * 64;
    for (int kc = 0; kc < 16; ++kc) {
      float4 cv = src[kc];
      cv.x *= sc; cv.y *= sc; cv.z *= sc; cv.w *= sc;
      const float* wr = wb + kc * 4 * 64;
#pragma unroll
      for (int kk = 0; kk < 4; ++kk) {
        const float c = (&cv.x)[kk];
#pragma unroll
        for (int o = 0; o < 64; ++o) h[o] = fmaf(c, wr[kk * 64 + o], h[o]);
      }
    }
  }
#pragma unroll
  for (int o = 0; o < 64; ++o) h[o] = fmaxf(h[o], 0.0f);
  float* outrow = out + (size_t)col * 64;
#pragma unroll
  for (int oc = 0; oc < 4; ++oc) {
    float m[16];
#pragma unroll
    for (int j = 0; j < 16; ++j) m[j] = sB2[oc * 16 + j];
#pragma unroll
    for (int k = 0; k < 64; ++k) {
      const float hk = h[k];
      const float* wr = sW2 + k * 64 + oc * 16;
#pragma unroll
      for (int j = 0; j < 16; ++j) m[j] = fmaf(hk, wr[j], m[j]);
    }
#pragma unroll
    for (int j = 0; j < 16; ++j) atomicAdd(outrow + oc * 16 + j, m[j]);
  }
}

// ---------------- launch ----------------

extern "C" void kernel_launch(void* const* d_in, const int* in_sizes, int n_in,
                              void* d_out, int out_size, void* d_ws, size_t ws_size,
                              hipStream_t stream) {
  const float* x  = (const float*)d_in[0];
  const int*   ei = (const int*)d_in[1];   // [2,E] int32
  const float* ea = (const float*)d_in[2];
  const float* W1 = (const float*)d_in[3];
  const float* b1 = (const float*)d_in[4];
  const float* W2 = (const float*)d_in[5];
  const float* b2 = (const float*)d_in[6];
  float* out = (float*)d_out;
  const int E = in_sizes[2];
  const int N = in_sizes[0] / 64;
  const int nb = (N + SCAN_B - 1) / SCAN_B;

  // ws layout (16B-aligned chunks):
  //   sre[E] int2 | cnt[N] | off[N] | posc[N] | bsum[SCAN_B] | A[N*64] f32 | Bp[N*64] f32
  auto align16 = [](size_t v) { return (v + 15) & ~(size_t)15; };
  size_t o_sre  = 0;
  size_t o_cnt  = align16(o_sre + (size_t)E * 8);
  size_t o_off  = align16(o_cnt + (size_t)N * 4);
  size_t o_posc = align16(o_off + (size_t)N * 4);
  size_t o_bsum = align16(o_posc + (size_t)N * 4);
  size_t o_A    = align16(o_bsum + (size_t)SCAN_B * 4);
  size_t o_Bp   = align16(o_A + (size_t)N * 64 * 4);
  size_t need   = o_Bp + (size_t)N * 64 * 4;

  if (ws_size < need || nb > SCAN_B) {
    hipMemsetAsync(d_out, 0, (size_t)out_size * sizeof(float), stream);
    const int blocks = (E + TPB - 1) / TPB;
    edge_mlp_atomic<<<blocks, TPB, 0, stream>>>(x, ei, ea, W1, b1, W2, b2, out, E);
    return;
  }

  char* ws = (char*)d_ws;
  int2* sre  = (int2*)(ws + o_sre);
  int*  cnt  = (int*)(ws + o_cnt);
  int*  off  = (int*)(ws + o_off);
  int*  posc = (int*)(ws + o_posc);
  int*  bsum = (int*)(ws + o_bsum);
  float* A   = (float*)(ws + o_A);
  float* Bp  = (float*)(ws + o_Bp);

  hipMemsetAsync(cnt, 0, (size_t)N * sizeof(int), stream);
  hipMemsetAsync(posc, 0, (size_t)N * sizeof(int), stream);

  const int eblocks = (E + TPB - 1) / TPB;
  const int nblocks4 = (4 * N + TPB - 1) / TPB;

  hist_kernel<<<eblocks, TPB, 0, stream>>>(ei, cnt, E);
  scan_local<<<nb, SCAN_B, 0, stream>>>(cnt, off, bsum, N);
  scan_bsum<<<1, SCAN_B, 0, stream>>>(bsum, nb);
  scatter_edges<<<eblocks, TPB, 0, stream>>>(ei, ea, off, bsum, posc, sre, E);
  precompute_ab<<<nblocks4, TPB, 0, stream>>>(x, W1, b1, A, Bp, N);
  node_accum<<<nblocks4, TPB, 0, stream>>>(A, Bp, sre, off, bsum, cnt, out, N);
  final_gemm<<<nblocks4, TPB, 0, stream>>>(out, W2, b2, cnt, N);
}

// Round 4
// 224.431 us; speedup vs baseline: 12.5282x; 1.2154x over previous
//
#include <hip/hip_runtime.h>

// ModularPathwayConv round 4:
//  R3 post-mortem: 272us total; scatter_edges 57us is transaction-bound
//  (800K random atomics + 800K random 8B writes). Changes:
//  1. hist returns per-edge rank (atomicAdd old value) -> scatter has ZERO atomics.
//  2. final_gemm fused into node_accum via __shfl_xor chunk exchange
//     (kills 51MB of H traffic, one dispatch, and the out memset).

constexpr int TPB = 256;
constexpr int SCAN_B = 1024;

// ---------------- CSR build ----------------

// cnt[col]++ and remember each edge's rank within its col segment
__global__ void hist_rank(const int* __restrict__ ei, int* __restrict__ cnt,
                          int* __restrict__ rank, int E) {
  int e = blockIdx.x * blockDim.x + threadIdx.x;
  if (e < E) rank[e] = atomicAdd(&cnt[ei[E + e]], 1);
}

__global__ __launch_bounds__(SCAN_B) void scan_local(const int* __restrict__ cnt,
                                                     int* __restrict__ off,
                                                     int* __restrict__ bsum, int N) {
  __shared__ int s[SCAN_B];
  int i = blockIdx.x * SCAN_B + (int)threadIdx.x;
  int v = (i < N) ? cnt[i] : 0;
  s[threadIdx.x] = v;
  __syncthreads();
  for (int d = 1; d < SCAN_B; d <<= 1) {
    int t = (threadIdx.x >= d) ? s[threadIdx.x - d] : 0;
    __syncthreads();
    s[threadIdx.x] += t;
    __syncthreads();
  }
  if (i < N) off[i] = s[threadIdx.x] - v;
  if (threadIdx.x == SCAN_B - 1) bsum[blockIdx.x] = s[threadIdx.x];
}

__global__ __launch_bounds__(SCAN_B) void scan_bsum(int* __restrict__ bsum, int nb) {
  __shared__ int s[SCAN_B];
  int v = ((int)threadIdx.x < nb) ? bsum[threadIdx.x] : 0;
  s[threadIdx.x] = v;
  __syncthreads();
  for (int d = 1; d < SCAN_B; d <<= 1) {
    int t = (threadIdx.x >= d) ? s[threadIdx.x - d] : 0;
    __syncthreads();
    s[threadIdx.x] += t;
    __syncthreads();
  }
  if ((int)threadIdx.x < nb) bsum[threadIdx.x] = s[threadIdx.x] - v;
}

// atomic-free scatter: pos = global CSR offset + precomputed rank
__global__ void scatter_edges(const int* __restrict__ ei, const float* __restrict__ ea,
                              const int* __restrict__ off, const int* __restrict__ bsum,
                              const int* __restrict__ rank, int2* __restrict__ sre, int E) {
  int e = blockIdx.x * blockDim.x + threadIdx.x;
  if (e >= E) return;
  int col = ei[E + e];
  int pos = off[col] + bsum[col >> 10] + rank[e];
  sre[pos] = make_int2(ei[e], __float_as_int(ea[e]));
}

// ---------------- per-node precompute: A = x@W1_top, Bp = x@W1_bot + b1 ----------------

__global__ __launch_bounds__(TPB) void precompute_ab(
    const float* __restrict__ x, const float* __restrict__ W1,
    const float* __restrict__ b1, float* __restrict__ A, float* __restrict__ Bp, int N)
{
  __shared__ float sW1[128 * 64];   // 32 KB
  __shared__ float sB1[64];
  for (int i = threadIdx.x; i < 128 * 64 / 4; i += TPB)
    reinterpret_cast<float4*>(sW1)[i] = reinterpret_cast<const float4*>(W1)[i];
  if (threadIdx.x < 64) sB1[threadIdx.x] = b1[threadIdx.x];
  __syncthreads();

  const int g = blockIdx.x * TPB + (int)threadIdx.x;
  const int n = g >> 2;
  const int q = g & 3;               // channel quarter
  if (n >= N) return;

  float4 aa[4], bb[4];
#pragma unroll
  for (int c = 0; c < 4; ++c) {
    aa[c] = make_float4(0.f, 0.f, 0.f, 0.f);
    bb[c] = *reinterpret_cast<const float4*>(sB1 + q * 16 + c * 4);
  }

  const float4* xrow = reinterpret_cast<const float4*>(x + (size_t)n * 64);
  for (int kc = 0; kc < 16; ++kc) {
    float4 xv = xrow[kc];
#pragma unroll
    for (int kk = 0; kk < 4; ++kk) {
      const float c0 = (&xv.x)[kk];
      const int k = kc * 4 + kk;
      const float* wa = sW1 + k * 64 + q * 16;
      const float* wb = sW1 + (64 + k) * 64 + q * 16;
#pragma unroll
      for (int c = 0; c < 4; ++c) {
        float4 wav = *reinterpret_cast<const float4*>(wa + c * 4);
        float4 wbv = *reinterpret_cast<const float4*>(wb + c * 4);
        aa[c].x = fmaf(c0, wav.x, aa[c].x); aa[c].y = fmaf(c0, wav.y, aa[c].y);
        aa[c].z = fmaf(c0, wav.z, aa[c].z); aa[c].w = fmaf(c0, wav.w, aa[c].w);
        bb[c].x = fmaf(c0, wbv.x, bb[c].x); bb[c].y = fmaf(c0, wbv.y, bb[c].y);
        bb[c].z = fmaf(c0, wbv.z, bb[c].z); bb[c].w = fmaf(c0, wbv.w, bb[c].w);
      }
    }
  }
  float4* arow = reinterpret_cast<float4*>(A + (size_t)n * 64) + q * 4;
  float4* brow = reinterpret_cast<float4*>(Bp + (size_t)n * 64) + q * 4;
#pragma unroll
  for (int c = 0; c < 4; ++c) { arow[c] = aa[c]; brow[c] = bb[c]; }
}

// ---------------- fused: H[n]=sum relu(ea*A[row]+Bp[n]); out[n]=H@W2+deg*b2 ----------------
// 4 lanes/node; zero atomics; H never touches memory (shfl_xor chunk exchange).

__global__ __launch_bounds__(TPB) void node_accum_gemm(
    const float* __restrict__ A, const float* __restrict__ Bp,
    const int2* __restrict__ sre, const int* __restrict__ off,
    const int* __restrict__ bsum, const int* __restrict__ cnt,
    const float* __restrict__ W2, const float* __restrict__ b2,
    float* __restrict__ out, int N)
{
  __shared__ float sW2[64 * 64];    // 16 KB
  __shared__ float sB2[64];
  for (int i = threadIdx.x; i < 64 * 64 / 4; i += TPB)
    reinterpret_cast<float4*>(sW2)[i] = reinterpret_cast<const float4*>(W2)[i];
  if (threadIdx.x < 64) sB2[threadIdx.x] = b2[threadIdx.x];
  __syncthreads();

  const int g = blockIdx.x * TPB + (int)threadIdx.x;
  const int n = g >> 2;
  const int q = g & 3;
  if (n >= N) return;   // all 4 lanes of a node exit together (n same within group)

  const int start = off[n] + bsum[n >> 10];
  const int deg = cnt[n];

  float4 bp[4];
  {
    const float4* brow = reinterpret_cast<const float4*>(Bp + (size_t)n * 64) + q * 4;
#pragma unroll
    for (int c = 0; c < 4; ++c) bp[c] = brow[c];
  }
  float4 acc4[4];
#pragma unroll
  for (int c = 0; c < 4; ++c) acc4[c] = make_float4(0.f, 0.f, 0.f, 0.f);

  int2 ed = (deg > 0) ? sre[start] : make_int2(0, 0);
  for (int t = 0; t < deg; ++t) {
    const int2 cur = ed;
    if (t + 1 < deg) ed = sre[start + t + 1];          // prefetch next edge
    const float eav = __int_as_float(cur.y);
    const float4* arow =
        reinterpret_cast<const float4*>(A + (size_t)cur.x * 64) + q * 4;
    float4 a0 = arow[0], a1 = arow[1], a2 = arow[2], a3 = arow[3];
#define STEP(av, c)                                                            \
    {                                                                          \
      float hx = fmaf(eav, av.x, bp[c].x); float hy = fmaf(eav, av.y, bp[c].y);\
      float hz = fmaf(eav, av.z, bp[c].z); float hw = fmaf(eav, av.w, bp[c].w);\
      acc4[c].x += fmaxf(hx, 0.f); acc4[c].y += fmaxf(hy, 0.f);                \
      acc4[c].z += fmaxf(hz, 0.f); acc4[c].w += fmaxf(hw, 0.f);                \
    }
    STEP(a0, 0) STEP(a1, 1) STEP(a2, 2) STEP(a3, 3)
#undef STEP
  }

  // --- fused second GEMM: lane q owns H chunk q (16 values in acc4) and
  // produces out channels [16q,16q+16). Exchange chunks via shfl_xor. ---
  float* accf = &acc4[0].x;          // 16 contiguous floats
  float m[16];
  {
    const float degf = (float)deg;
#pragma unroll
    for (int j = 0; j < 16; j += 4) {
      float4 b = *reinterpret_cast<const float4*>(sB2 + q * 16 + j);
      m[j] = degf * b.x; m[j + 1] = degf * b.y;
      m[j + 2] = degf * b.z; m[j + 3] = degf * b.w;
    }
  }
#pragma unroll
  for (int s = 0; s < 4; ++s) {
    const int r = q ^ s;             // which H chunk we're consuming this stage
    float hc[16];
#pragma unroll
    for (int j = 0; j < 16; ++j)
      hc[j] = (s == 0) ? accf[j] : __shfl_xor(accf[j], s);
#pragma unroll
    for (int kk = 0; kk < 16; ++kk) {
      const float hk = hc[kk];
      const float* wr = sW2 + (16 * r + kk) * 64 + q * 16;
#pragma unroll
      for (int j = 0; j < 16; j += 4) {
        // 2-way LDS bank aliasing across q (free per m136)
        float4 w = *reinterpret_cast<const float4*>(wr + j);
        m[j]     = fmaf(hk, w.x, m[j]);
        m[j + 1] = fmaf(hk, w.y, m[j + 1]);
        m[j + 2] = fmaf(hk, w.z, m[j + 2]);
        m[j + 3] = fmaf(hk, w.w, m[j + 3]);
      }
    }
  }

  float4* orow = reinterpret_cast<float4*>(out + (size_t)n * 64) + q * 4;
#pragma unroll
  for (int j = 0; j < 16; j += 4)
    orow[j / 4] = make_float4(m[j], m[j + 1], m[j + 2], m[j + 3]);
}

// ---------------- fallback (round-1 path, if ws too small) ----------------

__global__ __launch_bounds__(TPB) void edge_mlp_atomic(
    const float* __restrict__ x, const int* __restrict__ ei,
    const float* __restrict__ eattr, const float* __restrict__ W1,
    const float* __restrict__ b1, const float* __restrict__ W2,
    const float* __restrict__ b2, float* __restrict__ out, int E)
{
  __shared__ float sW1[128 * 64];
  __shared__ float sW2[64 * 64];
  __shared__ float sB1[64];
  __shared__ float sB2[64];
  for (int i = threadIdx.x; i < 128 * 64 / 4; i += TPB)
    reinterpret_cast<float4*>(sW1)[i] = reinterpret_cast<const float4*>(W1)[i];
  for (int i = threadIdx.x; i < 64 * 64 / 4; i += TPB)
    reinterpret_cast<float4*>(sW2)[i] = reinterpret_cast<const float4*>(W2)[i];
  if (threadIdx.x < 64) { sB1[threadIdx.x] = b1[threadIdx.x]; sB2[threadIdx.x] = b2[threadIdx.x]; }
  __syncthreads();
  const int e = blockIdx.x * TPB + (int)threadIdx.x;
  if (e >= E) return;
  const int row = ei[e];
  const int col = ei[E + e];
  const float scale = eattr[e];
  float h[64];
#pragma unroll
  for (int o = 0; o < 64; ++o) h[o] = sB1[o];
#pragma unroll
  for (int half = 0; half < 2; ++half) {
    const float4* src = reinterpret_cast<const float4*>(x + (size_t)(half ? col : row) * 64);
    const float sc = half ? 1.0f : scale;
    const float* wb = sW1 + half * 64 * 64;
    for (int kc = 0; kc < 16; ++kc) {
      float4 cv = src[kc];
      cv.x *= sc; cv.y *= sc; cv.z *= sc; cv.w *= sc;
      const float* wr = wb + kc * 4 * 64;
#pragma unroll
      for (int kk = 0; kk < 4; ++kk) {
        const float c = (&cv.x)[kk];
#pragma unroll
        for (int o = 0; o < 64; ++o) h[o] = fmaf(c, wr[kk * 64 + o], h[o]);
      }
    }
  }
#pragma unroll
  for (int o = 0; o < 64; ++o) h[o] = fmaxf(h[o], 0.0f);
  float* outrow = out + (size_t)col * 64;
#pragma unroll
  for (int oc = 0; oc < 4; ++oc) {
    float m[16];
#pragma unroll
    for (int j = 0; j < 16; ++j) m[j] = sB2[oc * 16 + j];
#pragma unroll
    for (int k = 0; k < 64; ++k) {
      const float hk = h[k];
      const float* wr = sW2 + k * 64 + oc * 16;
#pragma unroll
      for (int j = 0; j < 16; ++j) m[j] = fmaf(hk, wr[j], m[j]);
    }
#pragma unroll
    for (int j = 0; j < 16; ++j) atomicAdd(outrow + oc * 16 + j, m[j]);
  }
}

// ---------------- launch ----------------

extern "C" void kernel_launch(void* const* d_in, const int* in_sizes, int n_in,
                              void* d_out, int out_size, void* d_ws, size_t ws_size,
                              hipStream_t stream) {
  const float* x  = (const float*)d_in[0];
  const int*   ei = (const int*)d_in[1];   // [2,E] int32
  const float* ea = (const float*)d_in[2];
  const float* W1 = (const float*)d_in[3];
  const float* b1 = (const float*)d_in[4];
  const float* W2 = (const float*)d_in[5];
  const float* b2 = (const float*)d_in[6];
  float* out = (float*)d_out;
  const int E = in_sizes[2];
  const int N = in_sizes[0] / 64;
  const int nb = (N + SCAN_B - 1) / SCAN_B;

  // ws layout: sre[E] int2 | rank[E] | cnt[N] | off[N] | bsum[SCAN_B] | A[N*64] | Bp[N*64]
  auto align16 = [](size_t v) { return (v + 15) & ~(size_t)15; };
  size_t o_sre  = 0;
  size_t o_rank = align16(o_sre + (size_t)E * 8);
  size_t o_cnt  = align16(o_rank + (size_t)E * 4);
  size_t o_off  = align16(o_cnt + (size_t)N * 4);
  size_t o_bsum = align16(o_off + (size_t)N * 4);
  size_t o_A    = align16(o_bsum + (size_t)SCAN_B * 4);
  size_t o_Bp   = align16(o_A + (size_t)N * 64 * 4);
  size_t need   = o_Bp + (size_t)N * 64 * 4;

  if (ws_size < need || nb > SCAN_B) {
    hipMemsetAsync(d_out, 0, (size_t)out_size * sizeof(float), stream);
    const int blocks = (E + TPB - 1) / TPB;
    edge_mlp_atomic<<<blocks, TPB, 0, stream>>>(x, ei, ea, W1, b1, W2, b2, out, E);
    return;
  }

  char* ws = (char*)d_ws;
  int2* sre  = (int2*)(ws + o_sre);
  int*  rank = (int*)(ws + o_rank);
  int*  cnt  = (int*)(ws + o_cnt);
  int*  off  = (int*)(ws + o_off);
  int*  bsum = (int*)(ws + o_bsum);
  float* A   = (float*)(ws + o_A);
  float* Bp  = (float*)(ws + o_Bp);

  hipMemsetAsync(cnt, 0, (size_t)N * sizeof(int), stream);

  const int eblocks = (E + TPB - 1) / TPB;
  const int nblocks4 = (4 * N + TPB - 1) / TPB;

  hist_rank<<<eblocks, TPB, 0, stream>>>(ei, cnt, rank, E);
  scan_local<<<nb, SCAN_B, 0, stream>>>(cnt, off, bsum, N);
  scan_bsum<<<1, SCAN_B, 0, stream>>>(bsum, nb);
  scatter_edges<<<eblocks, TPB, 0, stream>>>(ei, ea, off, bsum, rank, sre, E);
  precompute_ab<<<nblocks4, TPB, 0, stream>>>(x, W1, b1, A, Bp, N);
  node_accum_gemm<<<nblocks4, TPB, 0, stream>>>(A, Bp, sre, off, bsum, cnt,
                                                W2, b2, out, N);
}

// Round 5
// 222.533 us; speedup vs baseline: 12.6350x; 1.0085x over previous
//
#include <hip/hip_runtime.h>
#include <hip/hip_bf16.h>

// ModularPathwayConv round 5:
//  R4 post-mortem: node_accum_gemm 62us is gather-fetch-bound (FETCH 106MB of
//  random A[row] reads). Fix: A and Bp stored as bf16 (halves gathered bytes;
//  bf16-A ~12.8MB nearly L2-resident) + software-pipelined A gather.
//  Error budget: bf16 rounding -> delta_out ~0.01 max vs threshold 0.28.

constexpr int TPB = 256;
constexpr int SCAN_B = 1024;

// ---------------- CSR build ----------------

__global__ void hist_rank(const int* __restrict__ ei, int* __restrict__ cnt,
                          int* __restrict__ rank, int E) {
  int e = blockIdx.x * blockDim.x + threadIdx.x;
  if (e < E) rank[e] = atomicAdd(&cnt[ei[E + e]], 1);
}

__global__ __launch_bounds__(SCAN_B) void scan_local(const int* __restrict__ cnt,
                                                     int* __restrict__ off,
                                                     int* __restrict__ bsum, int N) {
  __shared__ int s[SCAN_B];
  int i = blockIdx.x * SCAN_B + (int)threadIdx.x;
  int v = (i < N) ? cnt[i] : 0;
  s[threadIdx.x] = v;
  __syncthreads();
  for (int d = 1; d < SCAN_B; d <<= 1) {
    int t = (threadIdx.x >= d) ? s[threadIdx.x - d] : 0;
    __syncthreads();
    s[threadIdx.x] += t;
    __syncthreads();
  }
  if (i < N) off[i] = s[threadIdx.x] - v;
  if (threadIdx.x == SCAN_B - 1) bsum[blockIdx.x] = s[threadIdx.x];
}

__global__ __launch_bounds__(SCAN_B) void scan_bsum(int* __restrict__ bsum, int nb) {
  __shared__ int s[SCAN_B];
  int v = ((int)threadIdx.x < nb) ? bsum[threadIdx.x] : 0;
  s[threadIdx.x] = v;
  __syncthreads();
  for (int d = 1; d < SCAN_B; d <<= 1) {
    int t = (threadIdx.x >= d) ? s[threadIdx.x - d] : 0;
    __syncthreads();
    s[threadIdx.x] += t;
    __syncthreads();
  }
  if ((int)threadIdx.x < nb) bsum[threadIdx.x] = s[threadIdx.x] - v;
}

__global__ void scatter_edges(const int* __restrict__ ei, const float* __restrict__ ea,
                              const int* __restrict__ off, const int* __restrict__ bsum,
                              const int* __restrict__ rank, int2* __restrict__ sre, int E) {
  int e = blockIdx.x * blockDim.x + threadIdx.x;
  if (e >= E) return;
  int col = ei[E + e];
  int pos = off[col] + bsum[col >> 10] + rank[e];
  sre[pos] = make_int2(ei[e], __float_as_int(ea[e]));
}

// ---------------- bf16 pack helper ----------------

__device__ inline unsigned int pack_bf16(float lo, float hi) {
  __hip_bfloat16 l = __float2bfloat16(lo);
  __hip_bfloat16 h = __float2bfloat16(hi);
  unsigned short lu = *reinterpret_cast<unsigned short*>(&l);
  unsigned short hu = *reinterpret_cast<unsigned short*>(&h);
  return (unsigned int)lu | ((unsigned int)hu << 16);
}

// ---------------- per-node precompute: A = x@W1_top, Bp = x@W1_bot + b1 (bf16 out) ---

__global__ __launch_bounds__(TPB) void precompute_ab(
    const float* __restrict__ x, const float* __restrict__ W1,
    const float* __restrict__ b1, unsigned int* __restrict__ Abf,
    unsigned int* __restrict__ Bpbf, int N)
{
  __shared__ float sW1[128 * 64];   // 32 KB
  __shared__ float sB1[64];
  for (int i = threadIdx.x; i < 128 * 64 / 4; i += TPB)
    reinterpret_cast<float4*>(sW1)[i] = reinterpret_cast<const float4*>(W1)[i];
  if (threadIdx.x < 64) sB1[threadIdx.x] = b1[threadIdx.x];
  __syncthreads();

  const int g = blockIdx.x * TPB + (int)threadIdx.x;
  const int n = g >> 2;
  const int q = g & 3;               // channel quarter
  if (n >= N) return;

  float4 aa[4], bb[4];
#pragma unroll
  for (int c = 0; c < 4; ++c) {
    aa[c] = make_float4(0.f, 0.f, 0.f, 0.f);
    bb[c] = *reinterpret_cast<const float4*>(sB1 + q * 16 + c * 4);
  }

  const float4* xrow = reinterpret_cast<const float4*>(x + (size_t)n * 64);
  for (int kc = 0; kc < 16; ++kc) {
    float4 xv = xrow[kc];
#pragma unroll
    for (int kk = 0; kk < 4; ++kk) {
      const float c0 = (&xv.x)[kk];
      const int k = kc * 4 + kk;
      const float* wa = sW1 + k * 64 + q * 16;
      const float* wb = sW1 + (64 + k) * 64 + q * 16;
#pragma unroll
      for (int c = 0; c < 4; ++c) {
        float4 wav = *reinterpret_cast<const float4*>(wa + c * 4);
        float4 wbv = *reinterpret_cast<const float4*>(wb + c * 4);
        aa[c].x = fmaf(c0, wav.x, aa[c].x); aa[c].y = fmaf(c0, wav.y, aa[c].y);
        aa[c].z = fmaf(c0, wav.z, aa[c].z); aa[c].w = fmaf(c0, wav.w, aa[c].w);
        bb[c].x = fmaf(c0, wbv.x, bb[c].x); bb[c].y = fmaf(c0, wbv.y, bb[c].y);
        bb[c].z = fmaf(c0, wbv.z, bb[c].z); bb[c].w = fmaf(c0, wbv.w, bb[c].w);
      }
    }
  }

  // pack 16 fp32 -> 8 u32 (bf16 pairs); row = 32 u32 = 128 B
  const float* av = &aa[0].x;
  const float* bv = &bb[0].x;
  uint4 pa[2], pb[2];
#pragma unroll
  for (int h = 0; h < 2; ++h) {
    unsigned int* paw = &pa[h].x;
    unsigned int* pbw = &pb[h].x;
#pragma unroll
    for (int j = 0; j < 4; ++j) {
      paw[j] = pack_bf16(av[h * 8 + 2 * j], av[h * 8 + 2 * j + 1]);
      pbw[j] = pack_bf16(bv[h * 8 + 2 * j], bv[h * 8 + 2 * j + 1]);
    }
  }
  uint4* arow = reinterpret_cast<uint4*>(Abf) + (size_t)n * 8 + q * 2;
  uint4* brow = reinterpret_cast<uint4*>(Bpbf) + (size_t)n * 8 + q * 2;
  arow[0] = pa[0]; arow[1] = pa[1];
  brow[0] = pb[0]; brow[1] = pb[1];
}

// ---------------- fused: H[n]=sum relu(ea*A[row]+Bp[n]); out[n]=H@W2+deg*b2 ----------------
// 4 lanes/node; bf16 gather double-buffered; zero atomics; H stays in registers.

__global__ __launch_bounds__(TPB) void node_accum_gemm(
    const unsigned int* __restrict__ Abf, const unsigned int* __restrict__ Bpbf,
    const int2* __restrict__ sre, const int* __restrict__ off,
    const int* __restrict__ bsum, const int* __restrict__ cnt,
    const float* __restrict__ W2, const float* __restrict__ b2,
    float* __restrict__ out, int N)
{
  __shared__ float sW2[64 * 64];    // 16 KB
  __shared__ float sB2[64];
  for (int i = threadIdx.x; i < 64 * 64 / 4; i += TPB)
    reinterpret_cast<float4*>(sW2)[i] = reinterpret_cast<const float4*>(W2)[i];
  if (threadIdx.x < 64) sB2[threadIdx.x] = b2[threadIdx.x];
  __syncthreads();

  const int g = blockIdx.x * TPB + (int)threadIdx.x;
  const int n = g >> 2;
  const int q = g & 3;
  if (n >= N) return;

  const int start = off[n] + bsum[n >> 10];
  const int deg = cnt[n];

  // Bp chunk (16 ch) -> fp32 regs
  float bpf[16];
  {
    const uint4* brow = reinterpret_cast<const uint4*>(Bpbf) + (size_t)n * 8 + q * 2;
    uint4 b0 = brow[0], b1v = brow[1];
    const unsigned int bu[8] = {b0.x, b0.y, b0.z, b0.w, b1v.x, b1v.y, b1v.z, b1v.w};
#pragma unroll
    for (int j = 0; j < 8; ++j) {
      bpf[2 * j]     = __uint_as_float(bu[j] << 16);
      bpf[2 * j + 1] = __uint_as_float(bu[j] & 0xffff0000u);
    }
  }

  float acc[16];
#pragma unroll
  for (int j = 0; j < 16; ++j) acc[j] = 0.f;

  // software pipeline: e-record and A-row both double-buffered
  int2 e0 = (deg > 0) ? sre[start] : make_int2(0, 0);
  const uint4* ar0 = reinterpret_cast<const uint4*>(Abf) + (size_t)e0.x * 8 + q * 2;
  uint4 A0 = ar0[0], A1 = ar0[1];

  for (int t = 0; t < deg; ++t) {
    const float eav = __int_as_float(e0.y);
    uint4 C0 = A0, C1 = A1;
    if (t + 1 < deg) {
      int2 e1 = sre[start + t + 1];
      const uint4* ar1 =
          reinterpret_cast<const uint4*>(Abf) + (size_t)e1.x * 8 + q * 2;
      A0 = ar1[0]; A1 = ar1[1];
      e0 = e1;
    }
    const unsigned int au[8] = {C0.x, C0.y, C0.z, C0.w, C1.x, C1.y, C1.z, C1.w};
#pragma unroll
    for (int j = 0; j < 8; ++j) {
      float lo = __uint_as_float(au[j] << 16);
      float hi = __uint_as_float(au[j] & 0xffff0000u);
      acc[2 * j]     += fmaxf(fmaf(eav, lo, bpf[2 * j]), 0.f);
      acc[2 * j + 1] += fmaxf(fmaf(eav, hi, bpf[2 * j + 1]), 0.f);
    }
  }

  // --- fused second GEMM: lane q owns H chunk q, produces out ch [16q,16q+16) ---
  float m[16];
  {
    const float degf = (float)deg;
#pragma unroll
    for (int j = 0; j < 16; j += 4) {
      float4 b = *reinterpret_cast<const float4*>(sB2 + q * 16 + j);
      m[j] = degf * b.x; m[j + 1] = degf * b.y;
      m[j + 2] = degf * b.z; m[j + 3] = degf * b.w;
    }
  }
#pragma unroll
  for (int s = 0; s < 4; ++s) {
    const int r = q ^ s;             // H chunk consumed this stage
    float hc[16];
#pragma unroll
    for (int j = 0; j < 16; ++j)
      hc[j] = (s == 0) ? acc[j] : __shfl_xor(acc[j], s);
#pragma unroll
    for (int kk = 0; kk < 16; ++kk) {
      const float hk = hc[kk];
      const float* wr = sW2 + (16 * r + kk) * 64 + q * 16;
#pragma unroll
      for (int j = 0; j < 16; j += 4) {
        float4 w = *reinterpret_cast<const float4*>(wr + j);
        m[j]     = fmaf(hk, w.x, m[j]);
        m[j + 1] = fmaf(hk, w.y, m[j + 1]);
        m[j + 2] = fmaf(hk, w.z, m[j + 2]);
        m[j + 3] = fmaf(hk, w.w, m[j + 3]);
      }
    }
  }

  float4* orow = reinterpret_cast<float4*>(out + (size_t)n * 64) + q * 4;
#pragma unroll
  for (int j = 0; j < 16; j += 4)
    orow[j / 4] = make_float4(m[j], m[j + 1], m[j + 2], m[j + 3]);
}

// ---------------- fallback (round-1 path, if ws too small) ----------------

__global__ __launch_bounds__(TPB) void edge_mlp_atomic(
    const float* __restrict__ x, const int* __restrict__ ei,
    const float* __restrict__ eattr, const float* __restrict__ W1,
    const float* __restrict__ b1, const float* __restrict__ W2,
    const float* __restrict__ b2, float* __restrict__ out, int E)
{
  __shared__ float sW1[128 * 64];
  __shared__ float sW2[64 * 64];
  __shared__ float sB1[64];
  __shared__ float sB2[64];
  for (int i = threadIdx.x; i < 128 * 64 / 4; i += TPB)
    reinterpret_cast<float4*>(sW1)[i] = reinterpret_cast<const float4*>(W1)[i];
  for (int i = threadIdx.x; i < 64 * 64 / 4; i += TPB)
    reinterpret_cast<float4*>(sW2)[i] = reinterpret_cast<const float4*>(W2)[i];
  if (threadIdx.x < 64) { sB1[threadIdx.x] = b1[threadIdx.x]; sB2[threadIdx.x] = b2[threadIdx.x]; }
  __syncthreads();
  const int e = blockIdx.x * TPB + (int)threadIdx.x;
  if (e >= E) return;
  const int row = ei[e];
  const int col = ei[E + e];
  const float scale = eattr[e];
  float h[64];
#pragma unroll
  for (int o = 0; o < 64; ++o) h[o] = sB1[o];
#pragma unroll
  for (int half = 0; half < 2; ++half) {
    const float4* src = reinterpret_cast<const float4*>(x + (size_t)(half ? col : row) * 64);
    const float sc = half ? 1.0f : scale;
    const float* wb = sW1 + half * 64 * 64;
    for (int kc = 0; kc < 16; ++kc) {
      float4 cv = src[kc];
      cv.x *= sc; cv.y *= sc; cv.z *= sc; cv.w *= sc;
      const float* wr = wb + kc * 4 * 64;
#pragma unroll
      for (int kk = 0; kk < 4; ++kk) {
        const float c = (&cv.x)[kk];
#pragma unroll
        for (int o = 0; o < 64; ++o) h[o] = fmaf(c, wr[kk * 64 + o], h[o]);
      }
    }
  }
#pragma unroll
  for (int o = 0; o < 64; ++o) h[o] = fmaxf(h[o], 0.0f);
  float* outrow = out + (size_t)col * 64;
#pragma unroll
  for (int oc = 0; oc < 4; ++oc) {
    float m[16];
#pragma unroll
    for (int j = 0; j < 16; ++j) m[j] = sB2[oc * 16 + j];
#pragma unroll
    for (int k = 0; k < 64; ++k) {
      const float hk = h[k];
      const float* wr = sW2 + k * 64 + oc * 16;
#pragma unroll
      for (int j = 0; j < 16; ++j) m[j] = fmaf(hk, wr[j], m[j]);
    }
#pragma unroll
    for (int j = 0; j < 16; ++j) atomicAdd(outrow + oc * 16 + j, m[j]);
  }
}

// ---------------- launch ----------------

extern "C" void kernel_launch(void* const* d_in, const int* in_sizes, int n_in,
                              void* d_out, int out_size, void* d_ws, size_t ws_size,
                              hipStream_t stream) {
  const float* x  = (const float*)d_in[0];
  const int*   ei = (const int*)d_in[1];   // [2,E] int32
  const float* ea = (const float*)d_in[2];
  const float* W1 = (const float*)d_in[3];
  const float* b1 = (const float*)d_in[4];
  const float* W2 = (const float*)d_in[5];
  const float* b2 = (const float*)d_in[6];
  float* out = (float*)d_out;
  const int E = in_sizes[2];
  const int N = in_sizes[0] / 64;
  const int nb = (N + SCAN_B - 1) / SCAN_B;

  // ws layout: sre[E] int2 | rank[E] | cnt[N] | off[N] | bsum[SCAN_B]
  //            | Abf[N*32 u32] | Bpbf[N*32 u32]
  auto align16 = [](size_t v) { return (v + 15) & ~(size_t)15; };
  size_t o_sre  = 0;
  size_t o_rank = align16(o_sre + (size_t)E * 8);
  size_t o_cnt  = align16(o_rank + (size_t)E * 4);
  size_t o_off  = align16(o_cnt + (size_t)N * 4);
  size_t o_bsum = align16(o_off + (size_t)N * 4);
  size_t o_A    = align16(o_bsum + (size_t)SCAN_B * 4);
  size_t o_Bp   = align16(o_A + (size_t)N * 128);
  size_t need   = o_Bp + (size_t)N * 128;

  if (ws_size < need || nb > SCAN_B) {
    hipMemsetAsync(d_out, 0, (size_t)out_size * sizeof(float), stream);
    const int blocks = (E + TPB - 1) / TPB;
    edge_mlp_atomic<<<blocks, TPB, 0, stream>>>(x, ei, ea, W1, b1, W2, b2, out, E);
    return;
  }

  char* ws = (char*)d_ws;
  int2* sre  = (int2*)(ws + o_sre);
  int*  rank = (int*)(ws + o_rank);
  int*  cnt  = (int*)(ws + o_cnt);
  int*  off  = (int*)(ws + o_off);
  int*  bsum = (int*)(ws + o_bsum);
  unsigned int* Abf  = (unsigned int*)(ws + o_A);
  unsigned int* Bpbf = (unsigned int*)(ws + o_Bp);

  hipMemsetAsync(cnt, 0, (size_t)N * sizeof(int), stream);

  const int eblocks = (E + TPB - 1) / TPB;
  const int nblocks4 = (4 * N + TPB - 1) / TPB;

  hist_rank<<<eblocks, TPB, 0, stream>>>(ei, cnt, rank, E);
  scan_local<<<nb, SCAN_B, 0, stream>>>(cnt, off, bsum, N);
  scan_bsum<<<1, SCAN_B, 0, stream>>>(bsum, nb);
  scatter_edges<<<eblocks, TPB, 0, stream>>>(ei, ea, off, bsum, rank, sre, E);
  precompute_ab<<<nblocks4, TPB, 0, stream>>>(x, W1, b1, Abf, Bpbf, N);
  node_accum_gemm<<<nblocks4, TPB, 0, stream>>>(Abf, Bpbf, sre, off, bsum, cnt,
                                                W2, b2, out, N);
}